// Round 1
// baseline (2410.012 us; speedup 1.0000x reference)
//
#include <hip/hip_runtime.h>
#include <cstddef>

// Problem constants
#define Bq   256
#define Sq   2048
#define Iq   128
#define Hq   32
#define THq  96      // 3H
#define Kq   64
#define Oq   256
#define Mq   3

// d_out layout: outputs (B*S*O floats) then hiddens (B*S*H floats)
#define OUT_HID_OFF 134217728ull     // B*S*O = 256*2048*256
// GI overlay: inside outputs[b] region, occupying rows 1280..2047
#define GI_BSTRIDE  524288ull        // S*O floats per batch in outputs
#define GI_OFF      327680ull        // 524288 - S*96

// ---------------------------------------------------------------------------
// Kernel 1: GI[b][s][j] = b_ih[j] + sum_i inputs[b][s][i] * W_ih[j][i]
// One thread per (b,s) row. W_ih staged in LDS (48 KB), broadcast reads.
// ---------------------------------------------------------------------------
__global__ __launch_bounds__(256) void gi_gemm_kernel(
    const float* __restrict__ x, const float* __restrict__ Wih,
    const float* __restrict__ bih, float* __restrict__ gi_base)
{
    __shared__ float Wl[THq * Iq];   // 96*128 floats = 48 KB
    const int tid = threadIdx.x;

    // stage W_ih into LDS, coalesced float4
    {
        const float4* Wg4 = (const float4*)Wih;
        float4* Wl4 = (float4*)Wl;
        #pragma unroll
        for (int i = 0; i < 12; ++i)
            Wl4[tid + 256 * i] = Wg4[tid + 256 * i];
    }
    __syncthreads();

    const int r = blockIdx.x * 256 + tid;           // row in [0, B*S)
    const int b = r >> 11;
    const int s = r & 2047;

    // load full x row (128 floats) into registers
    const float4* xg = (const float4*)(x + (size_t)r * Iq);
    float4 xv[32];
    #pragma unroll
    for (int i = 0; i < 32; ++i) xv[i] = xg[i];

    float* out = gi_base + (size_t)b * GI_BSTRIDE + GI_OFF + (size_t)s * THq;

    #pragma unroll
    for (int half = 0; half < 2; ++half) {
        float acc[48];
        #pragma unroll
        for (int j = 0; j < 48; ++j) {
            const int row = half * 48 + j;
            const float4* w4 = (const float4*)(Wl + row * Iq);
            float p0 = bih[row], p1 = 0.f, p2 = 0.f, p3 = 0.f;
            #pragma unroll
            for (int i = 0; i < 32; ++i) {
                float4 w = w4[i];
                float4 xx = xv[i];
                p0 = fmaf(xx.x, w.x, p0);
                p1 = fmaf(xx.y, w.y, p1);
                p2 = fmaf(xx.z, w.z, p2);
                p3 = fmaf(xx.w, w.w, p3);
            }
            acc[j] = (p0 + p1) + (p2 + p3);
        }
        float4* o4 = (float4*)(out + half * 48);
        #pragma unroll
        for (int j4 = 0; j4 < 12; ++j4)
            o4[j4] = make_float4(acc[4*j4+0], acc[4*j4+1], acc[4*j4+2], acc[4*j4+3]);
    }
}

// ---------------------------------------------------------------------------
// Kernel 2: fused scan. 1 block per batch, 128 threads:
//   wave 0 (tid 0..63)  : GRU cell for step t          (lane l: rows l, 64+l)
//   wave 1 (tid 64..127): attention + output for t-1, kv-writes for t-1 < 3
// Cross-wave handoff of h via double-buffered LDS; one barrier per iteration.
// ---------------------------------------------------------------------------
__device__ __forceinline__ float sigmoid_f(float x) {
    return 1.f / (1.f + __expf(-x));
}
__device__ __forceinline__ float tanh_f(float x) {
    x = fminf(fmaxf(x, -30.f), 30.f);
    float e = __expf(-2.f * x);
    return (1.f - e) / (1.f + e);
}

__global__ __launch_bounds__(128) void scan_kernel(
    const float* __restrict__ Whh, const float* __restrict__ bhh,
    const float* __restrict__ Wk,  const float* __restrict__ bk,
    const float* __restrict__ Wq,  const float* __restrict__ bq,
    const float* __restrict__ Wv,  const float* __restrict__ bv,
    float* __restrict__ dout)
{
    const int tid = threadIdx.x;
    const int b = blockIdx.x;

    __shared__ __align__(16) float hbuf[2][Hq];
    __shared__ __align__(16) float keysS[Mq][Kq];
    __shared__ __align__(16) float valsS[Mq][Oq];

    // zero-init LDS (keys/vals must be 0 so w=0 lanes read clean zeros)
    if (tid < Hq) { hbuf[0][tid] = 0.f; hbuf[1][tid] = 0.f; }
    for (int i = tid; i < Mq * Kq; i += 128) ((float*)keysS)[i] = 0.f;
    for (int i = tid; i < Mq * Oq; i += 128) ((float*)valsS)[i] = 0.f;

    const float* gi_row = dout + (size_t)b * GI_BSTRIDE + GI_OFF;
    float* out_o = dout + (size_t)b * GI_BSTRIDE;                 // outputs[b]
    float* out_h = dout + OUT_HID_OFF + (size_t)b * (Sq * Hq);    // hiddens[b]

    if (tid < 64) {
        // ------------------------- cell wave -------------------------
        const int l = tid;
        const bool lo = (l < Hq);
        float wa[Hq], wb[Hq];
        #pragma unroll
        for (int k = 0; k < Hq; ++k) wa[k] = Whh[l * Hq + k];
        #pragma unroll
        for (int k = 0; k < Hq; ++k) wb[k] = lo ? Whh[(64 + l) * Hq + k] : 0.f;
        const float ba = bhh[l];
        const float bb = lo ? bhh[64 + l] : 0.f;
        float h_old = 0.f;

        // gi register prefetch pipeline (depth 4 covers ~900cyc HBM latency)
        const int PF = 4;
        float ga[4], gb[4];
        #pragma unroll
        for (int d = 0; d < PF; ++d) {
            ga[d] = gi_row[(size_t)d * THq + l];
            gb[d] = lo ? gi_row[(size_t)d * THq + 64 + l] : 0.f;
        }

        for (int t = 0; t <= Sq; ++t) {
            __syncthreads();
            if (t < Sq) {
                const float gia = ga[0];
                const float gib = gb[0];
                #pragma unroll
                for (int d = 0; d < PF - 1; ++d) { ga[d] = ga[d+1]; gb[d] = gb[d+1]; }
                const int tt = t + PF;
                if (tt < Sq) {
                    ga[PF-1] = gi_row[(size_t)tt * THq + l];
                    gb[PF-1] = lo ? gi_row[(size_t)tt * THq + 64 + l] : 0.f;
                } else { ga[PF-1] = 0.f; gb[PF-1] = 0.f; }

                const float4* h4 = (const float4*)hbuf[(t + 1) & 1];  // h_{t-1}
                float gha = ba, ghb = bb;
                #pragma unroll
                for (int kk = 0; kk < 8; ++kk) {
                    float4 hv = h4[kk];
                    gha = fmaf(hv.x, wa[4*kk+0], gha);
                    gha = fmaf(hv.y, wa[4*kk+1], gha);
                    gha = fmaf(hv.z, wa[4*kk+2], gha);
                    gha = fmaf(hv.w, wa[4*kk+3], gha);
                    ghb = fmaf(hv.x, wb[4*kk+0], ghb);
                    ghb = fmaf(hv.y, wb[4*kk+1], ghb);
                    ghb = fmaf(hv.z, wb[4*kk+2], ghb);
                    ghb = fmaf(hv.w, wb[4*kk+3], ghb);
                }
                const float xa = gia + gha;              // r-pre (l<32) / z-pre (l>=32)
                const float xz = __shfl(xa, l + 32, 64); // lanes <32 pull z-pre
                if (lo) {
                    const float r = sigmoid_f(xa);
                    const float z = sigmoid_f(xz);
                    const float n = tanh_f(gib + r * ghb);
                    const float hn = (1.f - z) * n + z * h_old;
                    h_old = hn;
                    hbuf[t & 1][l] = hn;
                    out_h[(size_t)t * Hq + l] = hn;
                }
            }
        }
    } else {
        // ------------------------- attention wave -------------------------
        const int k = tid - 64;          // 0..63
        float wqr[Hq], wkr[Hq];
        #pragma unroll
        for (int kk = 0; kk < Hq; ++kk) wqr[kk] = Wq[k * Hq + kk];
        #pragma unroll
        for (int kk = 0; kk < Hq; ++kk) wkr[kk] = Wk[k * Hq + kk];
        const float bqk = bq[k];
        const float bkk = bk[k];

        for (int t = 0; t <= Sq; ++t) {
            __syncthreads();
            if (t >= 1) {
                const int tp = t - 1;
                const float4* h4 = (const float4*)hbuf[tp & 1];
                float4 hr[8];
                #pragma unroll
                for (int kk = 0; kk < 8; ++kk) hr[kk] = h4[kk];

                // q_k = bq + h . Wq[k]
                float q = bqk;
                #pragma unroll
                for (int kk = 0; kk < 8; ++kk) {
                    q = fmaf(hr[kk].x, wqr[4*kk+0], q);
                    q = fmaf(hr[kk].y, wqr[4*kk+1], q);
                    q = fmaf(hr[kk].z, wqr[4*kk+2], q);
                    q = fmaf(hr[kk].w, wqr[4*kk+3], q);
                }
                // scores: 3 dot-products of length 64 via butterfly reduce
                float s0 = q * keysS[0][k];
                float s1 = q * keysS[1][k];
                float s2 = q * keysS[2][k];
                #pragma unroll
                for (int off = 1; off < 64; off <<= 1) {
                    s0 += __shfl_xor(s0, off, 64);
                    s1 += __shfl_xor(s1, off, 64);
                    s2 += __shfl_xor(s2, off, 64);
                }
                const int v = tp < Mq ? tp : Mq;
                float w0 = 0.f, w1 = 0.f, w2 = 0.f;
                if (v > 0) {
                    float mx = s0;
                    if (v > 1) mx = fmaxf(mx, s1);
                    if (v > 2) mx = fmaxf(mx, s2);
                    const float e0 = __expf(s0 - mx);
                    const float e1 = (v > 1) ? __expf(s1 - mx) : 0.f;
                    const float e2 = (v > 2) ? __expf(s2 - mx) : 0.f;
                    const float inv = 1.f / (e0 + e1 + e2);
                    w0 = e0 * inv; w1 = e1 * inv; w2 = e2 * inv;
                }
                // retrieved: lane k owns outputs 4k..4k+3
                const float4 a0 = ((const float4*)valsS[0])[k];
                const float4 a1 = ((const float4*)valsS[1])[k];
                const float4 a2 = ((const float4*)valsS[2])[k];
                float4 acc;
                acc.x = w0*a0.x + w1*a1.x + w2*a2.x;
                acc.y = w0*a0.y + w1*a1.y + w2*a2.y;
                acc.z = w0*a0.z + w1*a1.z + w2*a2.z;
                acc.w = w0*a0.w + w1*a1.w + w2*a2.w;
                ((float4*)(out_o + (size_t)tp * Oq))[k] = acc;

                // memory write (only first M steps)
                if (tp < Mq) {
                    float kv = bkk;
                    #pragma unroll
                    for (int kk = 0; kk < 8; ++kk) {
                        kv = fmaf(hr[kk].x, wkr[4*kk+0], kv);
                        kv = fmaf(hr[kk].y, wkr[4*kk+1], kv);
                        kv = fmaf(hr[kk].z, wkr[4*kk+2], kv);
                        kv = fmaf(hr[kk].w, wkr[4*kk+3], kv);
                    }
                    keysS[tp][k] = kv;
                    #pragma unroll
                    for (int j = 0; j < 4; ++j) {
                        const int o = 4 * k + j;
                        const float* wvr = Wv + o * Hq;
                        float vv = bv[o];
                        #pragma unroll
                        for (int kk = 0; kk < 8; ++kk) {
                            vv = fmaf(hr[kk].x, wvr[4*kk+0], vv);
                            vv = fmaf(hr[kk].y, wvr[4*kk+1], vv);
                            vv = fmaf(hr[kk].z, wvr[4*kk+2], vv);
                            vv = fmaf(hr[kk].w, wvr[4*kk+3], vv);
                        }
                        valsS[tp][o] = vv;
                    }
                }
            }
        }
    }
}

// ---------------------------------------------------------------------------
extern "C" void kernel_launch(void* const* d_in, const int* in_sizes, int n_in,
                              void* d_out, int out_size, void* d_ws, size_t ws_size,
                              hipStream_t stream) {
    const float* inputs = (const float*)d_in[0];
    const float* W_ih   = (const float*)d_in[1];
    const float* W_hh   = (const float*)d_in[2];
    const float* b_ih   = (const float*)d_in[3];
    const float* b_hh   = (const float*)d_in[4];
    const float* Wk     = (const float*)d_in[5];
    const float* bk     = (const float*)d_in[6];
    const float* Wq     = (const float*)d_in[7];
    const float* bq     = (const float*)d_in[8];
    const float* Wv     = (const float*)d_in[9];
    const float* bv     = (const float*)d_in[10];
    float* out = (float*)d_out;

    // Kernel 1: GI GEMM into the overlay region of d_out (tail of outputs[b])
    gi_gemm_kernel<<<(Bq * Sq) / 256, 256, 0, stream>>>(inputs, W_ih, b_ih, out);
    // Kernel 2: fused sequential scan + attention + output/hidden stores
    scan_kernel<<<Bq, 128, 0, stream>>>(W_hh, b_hh, Wk, bk, Wq, bq, Wv, bv, out);
}